// Round 2
// baseline (475.872 us; speedup 1.0000x reference)
//
#include <hip/hip_runtime.h>
#include <hip/hip_bf16.h>
#include <hip/hip_cooperative_groups.h>
#include <cstdint>
#include <cstddef>

namespace cg = cooperative_groups;

#define EPS 1e-8f

typedef __attribute__((ext_vector_type(8))) short short8;
typedef __attribute__((ext_vector_type(4))) float floatx4;

static constexpr int Bb = 16, Nn = 1024, Dd = 256, Kk = 256;
static constexpr int M = Bb * Nn;                      // 16384
static constexpr size_t PM = (size_t)M * 256;          // 4,194,304 elements per modality plane

// d_out element offsets (f32)
static constexpr size_t OUT_Z      = 0;
static constexpr size_t OUT_ASSIGN = 2 * PM;
static constexpr size_t OUT_SIM    = 4 * PM;
static constexpr size_t OUT_SEM    = 6 * PM;

// ws byte offsets
static constexpr size_t OFF_XN  = 0;                   // xn bf16 2*PM (aliased by abf later)
static constexpr size_t OFF_QB  = 16777216;            // q0 bf16 2*PM
static constexpr size_t OFF_PN  = 33554432;            // pn bf16 2*64K
static constexpr size_t OFF_PNT = 33816576;            // pnt bf16
static constexpr size_t OFF_U   = 34078720;            // u f32 2*M (fallback path only)
static constexpr size_t OFF_T   = 34209792;            // Tg 32 f32
static constexpr size_t OFF_SC  = 34209920;            // Sc 2*6*16*256 f32
static constexpr size_t OFF_CS  = 34406528;            // cs 2*16*256 f32
static constexpr size_t ZERO_OFF = OFF_T;
static constexpr size_t ZERO_SZ  = 128 + 196608 + 32768;
static constexpr int    NZ_FLOATS = (int)(ZERO_SZ / 4);

__device__ __forceinline__ unsigned short f2bf(float f) {
    unsigned int b = __float_as_uint(f);
    b += 0x7fffu + ((b >> 16) & 1u);          // RNE
    return (unsigned short)(b >> 16);
}
__device__ __forceinline__ float bf2f(unsigned short u) {
    return __uint_as_float(((unsigned int)u) << 16);
}
// padded index for the v vector in LDS: spreads 32-aligned float4 reads across bank quads
__device__ __forceinline__ int VP(int c) { return c + ((c >> 5) << 2); }

typedef const __attribute__((address_space(1))) unsigned int* gas_u32p;
typedef __attribute__((address_space(3))) unsigned int* las_u32p;
__device__ __forceinline__ void lds_cp16(const unsigned short* g, short* l) {
    __builtin_amdgcn_global_load_lds((gas_u32p)g, (las_u32p)l, 16, 0, 0);
}

// ---------------- x row-normalize -> bf16 ----------------
__global__ __launch_bounds__(256) void prep_kernel(const float* __restrict__ fr,
                                                   const float* __restrict__ fs,
                                                   unsigned short* __restrict__ xn) {
    int mod = blockIdx.y;
    int row = blockIdx.x * 4 + (threadIdx.x >> 6);
    int lane = threadIdx.x & 63;
    const float* src = (mod ? fs : fr) + (size_t)row * 256;
    float4 v = ((const float4*)src)[lane];
    float ss = v.x * v.x + v.y * v.y + v.z * v.z + v.w * v.w;
    #pragma unroll
    for (int m = 1; m < 64; m <<= 1) ss += __shfl_xor(ss, m);
    float sc = 1.0f / (sqrtf(ss) + EPS);
    ushort4 u4;
    u4.x = f2bf(v.x * sc); u4.y = f2bf(v.y * sc);
    u4.z = f2bf(v.z * sc); u4.w = f2bf(v.w * sc);
    *(ushort4*)(xn + (size_t)mod * PM + (size_t)row * 256 + lane * 4) = u4;
}

// ---------------- proto normalize (+ fused scratch zeroing) ----------------
__global__ __launch_bounds__(64) void proto_kernel(const float* __restrict__ pr,
                                                   const float* __restrict__ ps,
                                                   unsigned short* __restrict__ pn,
                                                   unsigned short* __restrict__ pnt,
                                                   float* __restrict__ zp) {
    int gid = blockIdx.x * 64 + threadIdx.x;           // 0..32767
    for (int i = gid; i < NZ_FLOATS; i += 32768) zp[i] = 0.f;

    int row = blockIdx.x & 255;
    int mod = blockIdx.x >> 8;
    const float* p = (mod ? ps : pr) + (size_t)row * 256;
    int lane = threadIdx.x;
    float4 v = ((const float4*)p)[lane];
    float ss = v.x * v.x + v.y * v.y + v.z * v.z + v.w * v.w;
    #pragma unroll
    for (int m = 1; m < 64; m <<= 1) ss += __shfl_xor(ss, m);
    float sc = 1.0f / (sqrtf(ss) + EPS);
    ushort4 u4;
    u4.x = f2bf(v.x * sc); u4.y = f2bf(v.y * sc);
    u4.z = f2bf(v.z * sc); u4.w = f2bf(v.w * sc);
    *(ushort4*)(pn + (size_t)mod * 65536 + (size_t)row * 256 + lane * 4) = u4;
    unsigned short* pt = pnt + (size_t)mod * 65536 + row;
    pt[(size_t)(lane * 4 + 0) * 256] = u4.x;
    pt[(size_t)(lane * 4 + 1) * 256] = u4.y;
    pt[(size_t)(lane * 4 + 2) * 256] = u4.z;
    pt[(size_t)(lane * 4 + 3) * 256] = u4.w;
}

// ---------------- MFMA GEMM, 128x128 tile, BK=64, global_load_lds + XOR swizzle ----------
// C[m][n] = sum_k A[m][k]*B[n][k], A/B bf16 row-major, row stride 256.
// MODE 0: A=xn, B=pn -> sim f32 + q0 bf16 + Tg atomics.   MODE 1: A=abf, B=pnt -> z f32.
template <int MODE>
__global__ __launch_bounds__(256) void gemm_kernel(const unsigned short* __restrict__ Asrc,
                                                   const unsigned short* __restrict__ Bsrc,
                                                   unsigned short* __restrict__ qb,
                                                   float* __restrict__ doutf,
                                                   float* __restrict__ Tg) {
    __shared__ short Al[8192];   // 128 rows x 64 shorts (8 chunks of 16B), chunk-swizzled
    __shared__ short Bl[8192];

    int bx = blockIdx.x;          // col tile 0..1
    int by = blockIdx.y;          // row tile 0..127
    int mod = blockIdx.z;
    int t = threadIdx.x;
    int lane = t & 63, wv = t >> 6;
    int wrow = (wv >> 1) * 64, wcol = (wv & 1) * 64;
    int g = lane >> 4, ml = lane & 15;

    const unsigned short* A0 = Asrc + (size_t)mod * PM + (size_t)by * 128 * 256;
    const unsigned short* B0 = Bsrc + (size_t)mod * 65536 + (size_t)bx * 128 * 256;

    floatx4 acc[4][4];
    #pragma unroll
    for (int i = 0; i < 4; i++)
        #pragma unroll
        for (int j = 0; j < 4; j++) acc[i][j] = (floatx4){0.f, 0.f, 0.f, 0.f};

    for (int kh = 0; kh < 4; kh++) {
        #pragma unroll
        for (int i = 0; i < 4; i++) {
            int sI = i * 256 + t;                 // linear 16B-slot index
            int r = sI >> 3, cs = sI & 7;
            int cg = cs ^ (r & 7);
            size_t goff = (size_t)r * 256 + kh * 64 + cg * 8;
            lds_cp16(A0 + goff, &Al[sI * 8]);
            lds_cp16(B0 + goff, &Bl[sI * 8]);
        }
        __syncthreads();
        #pragma unroll
        for (int ks = 0; ks < 2; ks++) {
            short8 af[4], bfr[4];
            int c = ks * 4 + g;
            #pragma unroll
            for (int mt = 0; mt < 4; mt++) {
                int row = wrow + mt * 16 + ml;
                af[mt] = *(const short8*)&Al[row * 64 + (c ^ (row & 7)) * 8];
            }
            #pragma unroll
            for (int nt = 0; nt < 4; nt++) {
                int row = wcol + nt * 16 + ml;
                bfr[nt] = *(const short8*)&Bl[row * 64 + (c ^ (row & 7)) * 8];
            }
            #pragma unroll
            for (int mt = 0; mt < 4; mt++)
                #pragma unroll
                for (int nt = 0; nt < 4; nt++)
                    acc[mt][nt] = __builtin_amdgcn_mfma_f32_16x16x32_bf16(af[mt], bfr[nt], acc[mt][nt], 0, 0, 0);
        }
        __syncthreads();
    }

    // epilogue: C/D layout col=lane&15, row=(lane>>4)*4+reg
    int g4 = g << 2;
    float tsum = 0.f;
    #pragma unroll
    for (int mt = 0; mt < 4; mt++)
        #pragma unroll
        for (int nt = 0; nt < 4; nt++)
            #pragma unroll
            for (int reg = 0; reg < 4; reg++) {
                float s = acc[mt][nt][reg];
                int row = by * 128 + wrow + mt * 16 + g4 + reg;
                int col = bx * 128 + wcol + nt * 16 + ml;
                size_t idx = (size_t)row * 256 + col;
                if (MODE == 0) {
                    doutf[OUT_SIM + (size_t)mod * PM + idx] = s;
                    unsigned short eb = f2bf(__expf(s * 20.0f));   // exp(sim/tau), tau=0.05
                    qb[(size_t)mod * PM + idx] = eb;
                    tsum += bf2f(eb);
                } else {
                    doutf[OUT_Z + (size_t)mod * PM + idx] = s;
                }
            }
    if (MODE == 0) {
        #pragma unroll
        for (int mk = 1; mk < 64; mk <<= 1) tsum += __shfl_xor(tsum, mk);
        if (lane == 0) atomicAdd(&Tg[mod * 16 + (by >> 3)], tsum);
    }
}

// ---------------- fused Sinkhorn: one persistent cooperative kernel ----------------
// Grid dim3(16,16,2) = 512 blocks: (tile, b, mod). Each block owns 64 rows, q tile
// resident in LDS across all 6 passes. Coupling via device atomics + grid syncs.
// __launch_bounds__(256,2): VGPR<=256 -> >=2 blocks/CU; LDS 39.3KB -> 4 blocks/CU.
// Capacity >= 1024 blocks >= grid 512: cooperative validation cannot reject.
__global__ __launch_bounds__(256, 2) void sinkhorn_fused(const unsigned short* __restrict__ qbg,
                                                         const float* __restrict__ Tg,
                                                         float* __restrict__ Sc,
                                                         float* __restrict__ cs,
                                                         float* __restrict__ doutf,
                                                         unsigned short* __restrict__ abf) {
    __shared__ unsigned short qt[64 * 264];   // padded row stride 264 -> balanced banks
    __shared__ float vpad[288];               // v (col scalers), padded via VP()
    __shared__ float unl[64];                 // u (row scalers), wave-private rows
    __shared__ float wsum[4][256];

    cg::grid_group gg = cg::this_grid();

    int tile = blockIdx.x, b = blockIdx.y, mod = blockIdx.z;
    int t = threadIdx.x;
    int wv = t >> 6, lane = t & 63;
    int r0 = t >> 3, qq = t & 7;

    size_t rowg0 = (size_t)b * 1024 + tile * 64;
    const unsigned short* qsrc = qbg + (size_t)mod * PM + rowg0 * 256;

    // ---- load 64x256 bf16 q tile into LDS (coalesced 16B chunks) ----
    #pragma unroll
    for (int i = 0; i < 8; i++) {
        int c = i * 256 + t;                  // 16B-chunk index 0..2047
        int row = c >> 5, cc = c & 31;
        *(short8*)&qt[row * 264 + cc * 8] = *(const short8*)(qsrc + (size_t)row * 256 + cc * 8);
    }
    float u0 = 1.0f / (Tg[mod * 16 + b] + EPS);   // Tg from prior kernel: plain load OK

    for (int pass = 1; pass <= 6; pass++) {
        // ---- v update (incremental; same chain as per-pass recompute) ----
        if (pass == 1) {
            vpad[VP(t)] = 1.0f;
        } else {
            // Sc written by device-scope atomics from other XCDs this kernel:
            // agent-scope load so a stale per-XCD L2 line can't be served.
            float scp = __hip_atomic_load(&Sc[((size_t)(mod * 6 + pass - 1) * 16 + b) * 256 + t],
                                          __ATOMIC_RELAXED, __HIP_MEMORY_SCOPE_AGENT);
            float v = vpad[VP(t)];
            vpad[VP(t)] = v * (1.0f / 256.0f) / (v * scp + EPS);
        }
        __syncthreads();                       // also covers qt-load visibility at pass 1

        // ---- phase A: row sums (8 lanes/row, rows r0 and r0+32) ----
        const float* vb0 = &vpad[VP(qq * 32)];
        #pragma unroll
        for (int h = 0; h < 2; h++) {
            int rr = r0 + h * 32;
            const unsigned short* qrow = &qt[rr * 264 + qq * 32];
            float sr = 0.f;
            #pragma unroll
            for (int i = 0; i < 4; i++) {
                short8 qv = *(const short8*)(qrow + i * 8);
                float4 va = *(const float4*)(vb0 + i * 8);
                float4 vb = *(const float4*)(vb0 + i * 8 + 4);
                sr += bf2f((unsigned short)qv[0]) * va.x + bf2f((unsigned short)qv[1]) * va.y
                    + bf2f((unsigned short)qv[2]) * va.z + bf2f((unsigned short)qv[3]) * va.w
                    + bf2f((unsigned short)qv[4]) * vb.x + bf2f((unsigned short)qv[5]) * vb.y
                    + bf2f((unsigned short)qv[6]) * vb.z + bf2f((unsigned short)qv[7]) * vb.w;
            }
            sr += __shfl_xor(sr, 1);
            sr += __shfl_xor(sr, 2);
            sr += __shfl_xor(sr, 4);
            float up = (pass == 1) ? u0 : unl[rr];
            float un;
            if (pass <= 5) un = up * (1.0f / 1024.0f) / (up * sr + EPS);
            else           un = up / (up * sr + EPS);
            if (qq == 0) unl[rr] = un;         // wave-private rows: no barrier needed
        }

        // ---- phase B: col partials; each wave covers its own phase-A rows ----
        float c0 = 0.f, c1 = 0.f, c2 = 0.f, c3 = 0.f;
        if (pass <= 5) {
            #pragma unroll
            for (int h = 0; h < 2; h++)
                #pragma unroll
                for (int k = 0; k < 8; k++) {
                    int rr = h * 32 + wv * 8 + k;
                    float unr = unl[rr];
                    ushort4 qv = *(const ushort4*)(&qt[rr * 264 + lane * 4]);
                    c0 += bf2f(qv.x) * unr;
                    c1 += bf2f(qv.y) * unr;
                    c2 += bf2f(qv.z) * unr;
                    c3 += bf2f(qv.w) * unr;
                }
        } else {
            float4 vv = *(const float4*)(&vpad[VP(lane * 4)]);
            float* aout = doutf + OUT_ASSIGN + (size_t)mod * PM;
            unsigned short* ab = abf + (size_t)mod * PM;
            #pragma unroll
            for (int h = 0; h < 2; h++)
                #pragma unroll
                for (int k = 0; k < 8; k++) {
                    int rr = h * 32 + wv * 8 + k;
                    float unr = unl[rr];
                    ushort4 qv = *(const ushort4*)(&qt[rr * 264 + lane * 4]);
                    float4 a = make_float4(bf2f(qv.x) * unr * vv.x, bf2f(qv.y) * unr * vv.y,
                                           bf2f(qv.z) * unr * vv.z, bf2f(qv.w) * unr * vv.w);
                    size_t ro = (rowg0 + rr) * 256;
                    *(float4*)(aout + ro + lane * 4) = a;
                    ushort4 o;
                    o.x = f2bf(a.x); o.y = f2bf(a.y); o.z = f2bf(a.z); o.w = f2bf(a.w);
                    *(ushort4*)(ab + ro + lane * 4) = o;
                    c0 += a.x; c1 += a.y; c2 += a.z; c3 += a.w;
                }
        }
        *(float4*)&wsum[wv][lane * 4] = make_float4(c0, c1, c2, c3);
        __syncthreads();
        float ssum = wsum[0][t] + wsum[1][t] + wsum[2][t] + wsum[3][t];
        if (pass <= 5) {
            atomicAdd(&Sc[((size_t)(mod * 6 + pass) * 16 + b) * 256 + t], ssum);
            gg.sync();                          // Sc[pass] complete before next v update
        } else {
            atomicAdd(&cs[((size_t)mod * 16 + b) * 256 + t], ssum);
        }
    }
}

// ---------------- fallback: original verified per-pass kernel ----------------
__global__ __launch_bounds__(256) void pass_kernel(const unsigned short* __restrict__ qbg,
                                                   float* __restrict__ u,
                                                   const float* __restrict__ Tg,
                                                   float* __restrict__ Sc,
                                                   float* __restrict__ cs,
                                                   float* __restrict__ doutf,
                                                   unsigned short* __restrict__ abf,
                                                   int pass) {
    __shared__ float vcur[256];
    __shared__ float unl[32];
    __shared__ float wsum[4][256];
    int tile = blockIdx.x, b = blockIdx.y, mod = blockIdx.z;
    int t = threadIdx.x;
    {
        float v = 1.0f;
        for (int j = 1; j < pass; j++) {
            float sc = Sc[((size_t)(mod * 6 + j) * 16 + b) * 256 + t];
            v = v * (1.0f / 256.0f) / (v * sc + EPS);
        }
        vcur[t] = v;
    }
    __syncthreads();

    int r = t >> 3, q = t & 7;
    size_t row = (size_t)b * 1024 + tile * 32 + r;
    const unsigned short* qrow = qbg + ((size_t)mod * M + row) * 256;
    const short8* q8 = (const short8*)(qrow + q * 32);
    const float4* v4 = (const float4*)(vcur + q * 32);
    float sr = 0.f;
    #pragma unroll
    for (int i = 0; i < 4; i++) {
        short8 qv = q8[i];
        float4 va = v4[2 * i], vb = v4[2 * i + 1];
        sr += bf2f((unsigned short)qv[0]) * va.x + bf2f((unsigned short)qv[1]) * va.y
            + bf2f((unsigned short)qv[2]) * va.z + bf2f((unsigned short)qv[3]) * va.w
            + bf2f((unsigned short)qv[4]) * vb.x + bf2f((unsigned short)qv[5]) * vb.y
            + bf2f((unsigned short)qv[6]) * vb.z + bf2f((unsigned short)qv[7]) * vb.w;
    }
    sr += __shfl_xor(sr, 1);
    sr += __shfl_xor(sr, 2);
    sr += __shfl_xor(sr, 4);

    float up = (pass == 1) ? 1.0f / (Tg[mod * 16 + b] + EPS) : u[(size_t)mod * M + row];
    float un;
    if (pass <= 5) un = up * (1.0f / 1024.0f) / (up * sr + EPS);
    else           un = up / (up * sr + EPS);
    if (q == 0) {
        if (pass <= 5) u[(size_t)mod * M + row] = un;
        unl[r] = un;
    }
    __syncthreads();

    int wv = t >> 6, lane = t & 63;
    float c0 = 0.f, c1 = 0.f, c2 = 0.f, c3 = 0.f;
    float4 vv = *(const float4*)(vcur + lane * 4);
    size_t rowbase = (size_t)mod * M + (size_t)b * 1024 + tile * 32;
    if (pass <= 5) {
        #pragma unroll
        for (int rr8 = 0; rr8 < 8; rr8++) {
            int rr = wv * 8 + rr8;
            float unr = unl[rr];
            ushort4 qv = *(const ushort4*)(qbg + (rowbase + rr) * 256 + lane * 4);
            c0 += bf2f(qv.x) * unr;
            c1 += bf2f(qv.y) * unr;
            c2 += bf2f(qv.z) * unr;
            c3 += bf2f(qv.w) * unr;
        }
    } else {
        float* aout = doutf + OUT_ASSIGN + (size_t)mod * PM;
        unsigned short* ab = abf + (size_t)mod * PM;
        #pragma unroll
        for (int rr8 = 0; rr8 < 8; rr8++) {
            int rr = wv * 8 + rr8;
            float unr = unl[rr];
            size_t ro = ((size_t)b * 1024 + tile * 32 + rr) * 256;
            ushort4 qv = *(const ushort4*)(qbg + (rowbase + rr) * 256 + lane * 4);
            float4 a = make_float4(bf2f(qv.x) * unr * vv.x, bf2f(qv.y) * unr * vv.y,
                                   bf2f(qv.z) * unr * vv.z, bf2f(qv.w) * unr * vv.w);
            *(float4*)(aout + ro + lane * 4) = a;
            ushort4 o;
            o.x = f2bf(a.x); o.y = f2bf(a.y); o.z = f2bf(a.z); o.w = f2bf(a.w);
            *(ushort4*)(ab + ro + lane * 4) = o;
            c0 += a.x; c1 += a.y; c2 += a.z; c3 += a.w;
        }
    }
    *(float4*)&wsum[wv][lane * 4] = make_float4(c0, c1, c2, c3);
    __syncthreads();
    {
        float ssum = wsum[0][t] + wsum[1][t] + wsum[2][t] + wsum[3][t];
        float* dst = (pass <= 5) ? &Sc[((size_t)(mod * 6 + pass) * 16 + b) * 256 + t]
                                 : &cs[((size_t)mod * 16 + b) * 256 + t];
        atomicAdd(dst, ssum);
    }
}

// ---------------- sem consistency scalar ----------------
__global__ __launch_bounds__(256) void sem_kernel(const float* __restrict__ cs,
                                                  float* __restrict__ doutf) {
    int t = threadIdx.x;
    float s = 0.f;
    #pragma unroll
    for (int b = 0; b < 16; b++)
        s += cs[b * 256 + t] * cs[4096 + b * 256 + t];
    #pragma unroll
    for (int mk = 1; mk < 64; mk <<= 1) s += __shfl_xor(s, mk);
    __shared__ float red[4];
    if ((t & 63) == 0) red[t >> 6] = s;
    __syncthreads();
    if (t == 0) {
        float tot = red[0] + red[1] + red[2] + red[3];
        float mv = tot / 16777216.0f;           // B*N*N
        mv = fminf(fmaxf(mv, 0.f), 1.f);
        doutf[OUT_SEM] = 1.0f - mv;
    }
}

extern "C" void kernel_launch(void* const* d_in, const int* in_sizes, int n_in,
                              void* d_out, int out_size, void* d_ws, size_t ws_size,
                              hipStream_t stream) {
    const float* f_rgb = (const float*)d_in[0];
    const float* f_sn  = (const float*)d_in[1];
    const float* p_rgb = (const float*)d_in[2];
    const float* p_sn  = (const float*)d_in[3];
    char* ws = (char*)d_ws;
    unsigned short* xn   = (unsigned short*)(ws + OFF_XN);
    unsigned short* abf  = (unsigned short*)(ws + OFF_XN);   // aliases xn (dead after gemm0)
    unsigned short* qb   = (unsigned short*)(ws + OFF_QB);
    unsigned short* pn   = (unsigned short*)(ws + OFF_PN);
    unsigned short* pnt  = (unsigned short*)(ws + OFF_PNT);
    float* u             = (float*)(ws + OFF_U);
    float* Tg            = (float*)(ws + OFF_T);
    float* Sc            = (float*)(ws + OFF_SC);
    float* cs            = (float*)(ws + OFF_CS);
    float* doutf         = (float*)d_out;

    proto_kernel<<<dim3(512), 64, 0, stream>>>(p_rgb, p_sn, pn, pnt, (float*)(ws + ZERO_OFF));
    prep_kernel<<<dim3(4096, 2), 256, 0, stream>>>(f_rgb, f_sn, xn);
    gemm_kernel<0><<<dim3(2, 128, 2), 256, 0, stream>>>(xn, pn, qb, doutf, Tg);

    const unsigned short* qbc = qb;
    const float* Tgc = Tg;
    void* args[] = {(void*)&qbc, (void*)&Tgc, (void*)&Sc, (void*)&cs, (void*)&doutf, (void*)&abf};
    hipError_t ce = hipLaunchCooperativeKernel(reinterpret_cast<void*>(sinkhorn_fused),
                                               dim3(16, 16, 2), dim3(256), args, 0, stream);
    if (ce != hipSuccess) {
        // fallback: verified 6-pass chain (round-0 behavior)
        for (int p = 1; p <= 6; p++)
            pass_kernel<<<dim3(32, 16, 2), 256, 0, stream>>>(qb, u, Tg, Sc, cs, doutf, abf, p);
    }

    gemm_kernel<1><<<dim3(2, 128, 2), 256, 0, stream>>>(abf, pnt, qb, doutf, Tg);
    sem_kernel<<<1, 256, 0, stream>>>(cs, doutf);
}

// Round 3
// 200.403 us; speedup vs baseline: 2.3746x; 2.3746x over previous
//
#include <hip/hip_runtime.h>
#include <hip/hip_bf16.h>
#include <cstdint>
#include <cstddef>

#define EPS 1e-8f

typedef __attribute__((ext_vector_type(8))) short short8;
typedef __attribute__((ext_vector_type(4))) float floatx4;

static constexpr int Bb = 16, Nn = 1024, Dd = 256, Kk = 256;
static constexpr int M = Bb * Nn;                      // 16384
static constexpr size_t PM = (size_t)M * 256;          // 4,194,304 elements per modality plane

// d_out element offsets (f32)
static constexpr size_t OUT_Z      = 0;
static constexpr size_t OUT_ASSIGN = 2 * PM;
static constexpr size_t OUT_SIM    = 4 * PM;
static constexpr size_t OUT_SEM    = 6 * PM;

// ws byte offsets
static constexpr size_t OFF_XN  = 0;                   // xn bf16 2*PM (aliased by abf later)
static constexpr size_t OFF_QB  = 16777216;            // q0 bf16 2*PM
static constexpr size_t OFF_PN  = 33554432;            // pn bf16 2*64K
static constexpr size_t OFF_PNT = 33816576;            // pnt bf16
static constexpr size_t OFF_U   = 34078720;            // u f32 2*M
static constexpr size_t OFF_T   = 34209792;            // Tg 32 f32
static constexpr size_t OFF_SC  = 34209920;            // Sc 2*6*16*256 f32
static constexpr size_t OFF_CS  = 34406528;            // cs 2*16*256 f32
static constexpr size_t ZERO_OFF = OFF_T;
static constexpr size_t ZERO_SZ  = 128 + 196608 + 32768;
static constexpr int    NZ_FLOATS = (int)(ZERO_SZ / 4);

__device__ __forceinline__ unsigned short f2bf(float f) {
    unsigned int b = __float_as_uint(f);
    b += 0x7fffu + ((b >> 16) & 1u);          // RNE
    return (unsigned short)(b >> 16);
}
__device__ __forceinline__ float bf2f(unsigned short u) {
    return __uint_as_float(((unsigned int)u) << 16);
}

typedef const __attribute__((address_space(1))) unsigned int* gas_u32p;
typedef __attribute__((address_space(3))) unsigned int* las_u32p;
__device__ __forceinline__ void lds_cp16(const unsigned short* g, short* l) {
    __builtin_amdgcn_global_load_lds((gas_u32p)g, (las_u32p)l, 16, 0, 0);
}

// ---------------- x row-normalize -> bf16 ----------------
__global__ __launch_bounds__(256) void prep_kernel(const float* __restrict__ fr,
                                                   const float* __restrict__ fs,
                                                   unsigned short* __restrict__ xn) {
    int mod = blockIdx.y;
    int row = blockIdx.x * 4 + (threadIdx.x >> 6);
    int lane = threadIdx.x & 63;
    const float* src = (mod ? fs : fr) + (size_t)row * 256;
    float4 v = ((const float4*)src)[lane];
    float ss = v.x * v.x + v.y * v.y + v.z * v.z + v.w * v.w;
    #pragma unroll
    for (int m = 1; m < 64; m <<= 1) ss += __shfl_xor(ss, m);
    float sc = 1.0f / (sqrtf(ss) + EPS);
    ushort4 u4;
    u4.x = f2bf(v.x * sc); u4.y = f2bf(v.y * sc);
    u4.z = f2bf(v.z * sc); u4.w = f2bf(v.w * sc);
    *(ushort4*)(xn + (size_t)mod * PM + (size_t)row * 256 + lane * 4) = u4;
}

// ---------------- proto normalize (+ fused scratch zeroing) ----------------
__global__ __launch_bounds__(64) void proto_kernel(const float* __restrict__ pr,
                                                   const float* __restrict__ ps,
                                                   unsigned short* __restrict__ pn,
                                                   unsigned short* __restrict__ pnt,
                                                   float* __restrict__ zp) {
    int gid = blockIdx.x * 64 + threadIdx.x;           // 0..32767
    for (int i = gid; i < NZ_FLOATS; i += 32768) zp[i] = 0.f;

    int row = blockIdx.x & 255;
    int mod = blockIdx.x >> 8;
    const float* p = (mod ? ps : pr) + (size_t)row * 256;
    int lane = threadIdx.x;
    float4 v = ((const float4*)p)[lane];
    float ss = v.x * v.x + v.y * v.y + v.z * v.z + v.w * v.w;
    #pragma unroll
    for (int m = 1; m < 64; m <<= 1) ss += __shfl_xor(ss, m);
    float sc = 1.0f / (sqrtf(ss) + EPS);
    ushort4 u4;
    u4.x = f2bf(v.x * sc); u4.y = f2bf(v.y * sc);
    u4.z = f2bf(v.z * sc); u4.w = f2bf(v.w * sc);
    *(ushort4*)(pn + (size_t)mod * 65536 + (size_t)row * 256 + lane * 4) = u4;
    unsigned short* pt = pnt + (size_t)mod * 65536 + row;
    pt[(size_t)(lane * 4 + 0) * 256] = u4.x;
    pt[(size_t)(lane * 4 + 1) * 256] = u4.y;
    pt[(size_t)(lane * 4 + 2) * 256] = u4.z;
    pt[(size_t)(lane * 4 + 3) * 256] = u4.w;
}

// ---------------- MFMA GEMM v2: B-panel fully K-resident in LDS ----------------
// C[m][n] = sum_k A[m][k]*B[n][k], A/B bf16 row-major, row stride 256 (= full K).
// Block: 256 thr, 128x128 output tile. B panel [128 cols][256 k] = 64 KB staged ONCE
// (pre-swizzled global source -> linear global_load_lds dest; XOR (col&7)<<4 on bytes
// spreads frag reads over all 8 aligned 16B bank-groups = optimal for ds_read_b128).
// A staged per kh ([128][64] = 16 KB, original verified swizzle). LDS 80 KB -> 2 blk/CU.
// MODE 0: A=xn, B=pn -> sim f32 + q0 bf16 + Tg atomics.   MODE 1: A=abf, B=pnt -> z f32.
template <int MODE>
__global__ __launch_bounds__(256) void gemm_kernel(const unsigned short* __restrict__ Asrc,
                                                   const unsigned short* __restrict__ Bsrc,
                                                   unsigned short* __restrict__ qb,
                                                   float* __restrict__ doutf,
                                                   float* __restrict__ Tg) {
    __shared__ short Al[8192];    // 128 rows x 64 shorts, 16B-chunk XOR swizzle
    __shared__ short Bl[32768];   // 128 cols x 256 shorts, 16B-chunk XOR swizzle

    int bx = blockIdx.x;          // col tile 0..1
    int by = blockIdx.y;          // row tile 0..127
    int mod = blockIdx.z;
    int t = threadIdx.x;
    int lane = t & 63, wv = t >> 6;
    int wrow = (wv >> 1) * 64, wcol = (wv & 1) * 64;
    int g = lane >> 4, ml = lane & 15;

    const unsigned short* A0 = Asrc + (size_t)mod * PM + (size_t)by * 128 * 256;
    const unsigned short* B0 = Bsrc + (size_t)mod * 65536 + (size_t)bx * 128 * 256;

    // ---- stage whole B panel once (4096 16B chunks; src pre-swizzled) ----
    #pragma unroll
    for (int i = 0; i < 16; i++) {
        int cb = i * 256 + t;                 // 16B-chunk index 0..4095
        int col = cb >> 5;                    // 32 chunks per col-row
        int w = (cb * 8) & 255;               // short offset within the col's 256-short row
        int ws = w ^ ((col & 7) << 3);        // involution (affects bits 3-5, w<256 stays)
        lds_cp16(B0 + (size_t)col * 256 + ws, &Bl[cb * 8]);
    }

    floatx4 acc[4][4];
    #pragma unroll
    for (int i = 0; i < 4; i++)
        #pragma unroll
        for (int j = 0; j < 4; j++) acc[i][j] = (floatx4){0.f, 0.f, 0.f, 0.f};

    for (int kh = 0; kh < 4; kh++) {
        // ---- stage A chunk [128][64] (original verified swizzle) ----
        #pragma unroll
        for (int i = 0; i < 4; i++) {
            int sI = i * 256 + t;             // linear 16B-slot index 0..1023
            int r = sI >> 3, cs = sI & 7;
            int cg = cs ^ (r & 7);
            size_t goff = (size_t)r * 256 + kh * 64 + cg * 8;
            lds_cp16(A0 + goff, &Al[sI * 8]);
        }
        __syncthreads();                      // drains B-stage (first iter) + A-stage
        #pragma unroll
        for (int ks = 0; ks < 2; ks++) {
            short8 af[4], bfr[4];
            int c = ks * 4 + g;
            #pragma unroll
            for (int mt = 0; mt < 4; mt++) {
                int row = wrow + mt * 16 + ml;
                af[mt] = *(const short8*)&Al[row * 64 + (c ^ (row & 7)) * 8];
            }
            int kko = kh * 64 + ks * 32 + g * 8;   // global-K short offset of this frag slice
            #pragma unroll
            for (int nt = 0; nt < 4; nt++) {
                int col = wcol + nt * 16 + ml;
                bfr[nt] = *(const short8*)&Bl[col * 256 + (kko ^ ((col & 7) << 3))];
            }
            #pragma unroll
            for (int mt = 0; mt < 4; mt++)
                #pragma unroll
                for (int nt = 0; nt < 4; nt++)
                    acc[mt][nt] = __builtin_amdgcn_mfma_f32_16x16x32_bf16(af[mt], bfr[nt], acc[mt][nt], 0, 0, 0);
        }
        __syncthreads();                      // all reads of Al done before overwrite
    }

    // epilogue: C/D layout col=lane&15, row=(lane>>4)*4+reg
    int g4 = g << 2;
    float tsum = 0.f;
    #pragma unroll
    for (int mt = 0; mt < 4; mt++)
        #pragma unroll
        for (int nt = 0; nt < 4; nt++)
            #pragma unroll
            for (int reg = 0; reg < 4; reg++) {
                float s = acc[mt][nt][reg];
                int row = by * 128 + wrow + mt * 16 + g4 + reg;
                int col = bx * 128 + wcol + nt * 16 + ml;
                size_t idx = (size_t)row * 256 + col;
                if (MODE == 0) {
                    doutf[OUT_SIM + (size_t)mod * PM + idx] = s;
                    unsigned short eb = f2bf(__expf(s * 20.0f));   // exp(sim/tau), tau=0.05
                    qb[(size_t)mod * PM + idx] = eb;
                    tsum += bf2f(eb);
                } else {
                    doutf[OUT_Z + (size_t)mod * PM + idx] = s;
                }
            }
    if (MODE == 0) {
        #pragma unroll
        for (int mk = 1; mk < 64; mk <<= 1) tsum += __shfl_xor(tsum, mk);
        __shared__ float tred[4];
        if (lane == 0) tred[wv] = tsum;
        __syncthreads();
        if (t == 0) atomicAdd(&Tg[mod * 16 + (by >> 3)], tred[0] + tred[1] + tred[2] + tred[3]);
    }
}

// ---------------- Sinkhorn pass over bf16 q0 (verified round-0 kernel) ----------------
__global__ __launch_bounds__(256) void pass_kernel(const unsigned short* __restrict__ qbg,
                                                   float* __restrict__ u,
                                                   const float* __restrict__ Tg,
                                                   float* __restrict__ Sc,
                                                   float* __restrict__ cs,
                                                   float* __restrict__ doutf,
                                                   unsigned short* __restrict__ abf,
                                                   int pass) {
    __shared__ float vcur[256];
    __shared__ float unl[32];
    __shared__ float wsum[4][256];
    int tile = blockIdx.x, b = blockIdx.y, mod = blockIdx.z;
    int t = threadIdx.x;
    {
        float v = 1.0f;
        for (int j = 1; j < pass; j++) {
            float sc = Sc[((size_t)(mod * 6 + j) * 16 + b) * 256 + t];
            v = v * (1.0f / 256.0f) / (v * sc + EPS);
        }
        vcur[t] = v;
    }
    __syncthreads();

    int r = t >> 3, q = t & 7;
    size_t row = (size_t)b * 1024 + tile * 32 + r;
    const unsigned short* qrow = qbg + ((size_t)mod * M + row) * 256;
    const short8* q8 = (const short8*)(qrow + q * 32);
    const float4* v4 = (const float4*)(vcur + q * 32);
    float sr = 0.f;
    #pragma unroll
    for (int i = 0; i < 4; i++) {
        short8 qv = q8[i];
        float4 va = v4[2 * i], vb = v4[2 * i + 1];
        sr += bf2f((unsigned short)qv[0]) * va.x + bf2f((unsigned short)qv[1]) * va.y
            + bf2f((unsigned short)qv[2]) * va.z + bf2f((unsigned short)qv[3]) * va.w
            + bf2f((unsigned short)qv[4]) * vb.x + bf2f((unsigned short)qv[5]) * vb.y
            + bf2f((unsigned short)qv[6]) * vb.z + bf2f((unsigned short)qv[7]) * vb.w;
    }
    sr += __shfl_xor(sr, 1);
    sr += __shfl_xor(sr, 2);
    sr += __shfl_xor(sr, 4);

    float up = (pass == 1) ? 1.0f / (Tg[mod * 16 + b] + EPS) : u[(size_t)mod * M + row];
    float un;
    if (pass <= 5) un = up * (1.0f / 1024.0f) / (up * sr + EPS);
    else           un = up / (up * sr + EPS);
    if (q == 0) {
        if (pass <= 5) u[(size_t)mod * M + row] = un;
        unl[r] = un;
    }
    __syncthreads();

    int wv = t >> 6, lane = t & 63;
    float c0 = 0.f, c1 = 0.f, c2 = 0.f, c3 = 0.f;
    float4 vv = *(const float4*)(vcur + lane * 4);
    size_t rowbase = (size_t)mod * M + (size_t)b * 1024 + tile * 32;
    if (pass <= 5) {
        #pragma unroll
        for (int rr8 = 0; rr8 < 8; rr8++) {
            int rr = wv * 8 + rr8;
            float unr = unl[rr];
            ushort4 qv = *(const ushort4*)(qbg + (rowbase + rr) * 256 + lane * 4);
            c0 += bf2f(qv.x) * unr;
            c1 += bf2f(qv.y) * unr;
            c2 += bf2f(qv.z) * unr;
            c3 += bf2f(qv.w) * unr;
        }
    } else {
        float* aout = doutf + OUT_ASSIGN + (size_t)mod * PM;
        unsigned short* ab = abf + (size_t)mod * PM;
        #pragma unroll
        for (int rr8 = 0; rr8 < 8; rr8++) {
            int rr = wv * 8 + rr8;
            float unr = unl[rr];
            size_t ro = ((size_t)b * 1024 + tile * 32 + rr) * 256;
            ushort4 qv = *(const ushort4*)(qbg + (rowbase + rr) * 256 + lane * 4);
            float4 a = make_float4(bf2f(qv.x) * unr * vv.x, bf2f(qv.y) * unr * vv.y,
                                   bf2f(qv.z) * unr * vv.z, bf2f(qv.w) * unr * vv.w);
            *(float4*)(aout + ro + lane * 4) = a;
            ushort4 o;
            o.x = f2bf(a.x); o.y = f2bf(a.y); o.z = f2bf(a.z); o.w = f2bf(a.w);
            *(ushort4*)(ab + ro + lane * 4) = o;
            c0 += a.x; c1 += a.y; c2 += a.z; c3 += a.w;
        }
    }
    *(float4*)&wsum[wv][lane * 4] = make_float4(c0, c1, c2, c3);
    __syncthreads();
    {
        float ssum = wsum[0][t] + wsum[1][t] + wsum[2][t] + wsum[3][t];
        float* dst = (pass <= 5) ? &Sc[((size_t)(mod * 6 + pass) * 16 + b) * 256 + t]
                                 : &cs[((size_t)mod * 16 + b) * 256 + t];
        atomicAdd(dst, ssum);
    }
}

// ---------------- sem consistency scalar ----------------
__global__ __launch_bounds__(256) void sem_kernel(const float* __restrict__ cs,
                                                  float* __restrict__ doutf) {
    int t = threadIdx.x;
    float s = 0.f;
    #pragma unroll
    for (int b = 0; b < 16; b++)
        s += cs[b * 256 + t] * cs[4096 + b * 256 + t];
    #pragma unroll
    for (int mk = 1; mk < 64; mk <<= 1) s += __shfl_xor(s, mk);
    __shared__ float red[4];
    if ((t & 63) == 0) red[t >> 6] = s;
    __syncthreads();
    if (t == 0) {
        float tot = red[0] + red[1] + red[2] + red[3];
        float mv = tot / 16777216.0f;           // B*N*N
        mv = fminf(fmaxf(mv, 0.f), 1.f);
        doutf[OUT_SEM] = 1.0f - mv;
    }
}

extern "C" void kernel_launch(void* const* d_in, const int* in_sizes, int n_in,
                              void* d_out, int out_size, void* d_ws, size_t ws_size,
                              hipStream_t stream) {
    const float* f_rgb = (const float*)d_in[0];
    const float* f_sn  = (const float*)d_in[1];
    const float* p_rgb = (const float*)d_in[2];
    const float* p_sn  = (const float*)d_in[3];
    char* ws = (char*)d_ws;
    unsigned short* xn   = (unsigned short*)(ws + OFF_XN);
    unsigned short* abf  = (unsigned short*)(ws + OFF_XN);   // aliases xn (dead after gemm0)
    unsigned short* qb   = (unsigned short*)(ws + OFF_QB);
    unsigned short* pn   = (unsigned short*)(ws + OFF_PN);
    unsigned short* pnt  = (unsigned short*)(ws + OFF_PNT);
    float* u             = (float*)(ws + OFF_U);
    float* Tg            = (float*)(ws + OFF_T);
    float* Sc            = (float*)(ws + OFF_SC);
    float* cs            = (float*)(ws + OFF_CS);
    float* doutf         = (float*)d_out;

    proto_kernel<<<dim3(512), 64, 0, stream>>>(p_rgb, p_sn, pn, pnt, (float*)(ws + ZERO_OFF));
    prep_kernel<<<dim3(4096, 2), 256, 0, stream>>>(f_rgb, f_sn, xn);
    gemm_kernel<0><<<dim3(2, 128, 2), 256, 0, stream>>>(xn, pn, qb, doutf, Tg);
    for (int p = 1; p <= 6; p++)
        pass_kernel<<<dim3(32, 16, 2), 256, 0, stream>>>(qb, u, Tg, Sc, cs, doutf, abf, p);
    gemm_kernel<1><<<dim3(2, 128, 2), 256, 0, stream>>>(abf, pnt, qb, doutf, Tg);
    sem_kernel<<<1, 256, 0, stream>>>(cs, doutf);
}

// Round 4
// 192.099 us; speedup vs baseline: 2.4772x; 1.0432x over previous
//
#include <hip/hip_runtime.h>
#include <hip/hip_bf16.h>
#include <cstdint>
#include <cstddef>

#define EPS 1e-8f

typedef __attribute__((ext_vector_type(8))) short short8;
typedef __attribute__((ext_vector_type(4))) float floatx4;

static constexpr int Bb = 16, Nn = 1024, Dd = 256, Kk = 256;
static constexpr int M = Bb * Nn;                      // 16384
static constexpr size_t PM = (size_t)M * 256;          // 4,194,304 elements per modality plane

// d_out element offsets (f32)
static constexpr size_t OUT_Z      = 0;
static constexpr size_t OUT_ASSIGN = 2 * PM;
static constexpr size_t OUT_SIM    = 4 * PM;
static constexpr size_t OUT_SEM    = 6 * PM;

// ws byte offsets
static constexpr size_t OFF_QB  = 16777216;            // q0 bf16 2*PM
static constexpr size_t OFF_PN  = 33554432;            // pn bf16 2*64K
static constexpr size_t OFF_PNT = 33816576;            // pnt bf16
static constexpr size_t OFF_U   = 34078720;            // u f32 2*M
static constexpr size_t OFF_T   = 34209792;            // Tg 32 f32
static constexpr size_t OFF_SC  = 34209920;            // Sc 2*6*16*256 f32
static constexpr size_t OFF_CS  = 34406528;            // cs 2*16*256 f32
static constexpr size_t ZERO_OFF = OFF_T;
static constexpr size_t ZERO_SZ  = 128 + 196608 + 32768;
static constexpr int    NZ_FLOATS = (int)(ZERO_SZ / 4);

__device__ __forceinline__ unsigned short f2bf(float f) {
    unsigned int b = __float_as_uint(f);
    b += 0x7fffu + ((b >> 16) & 1u);          // RNE
    return (unsigned short)(b >> 16);
}
__device__ __forceinline__ float bf2f(unsigned short u) {
    return __uint_as_float(((unsigned int)u) << 16);
}

typedef const __attribute__((address_space(1))) unsigned int* gas_u32p;
typedef __attribute__((address_space(3))) unsigned int* las_u32p;
__device__ __forceinline__ void lds_cp16(const unsigned short* g, short* l) {
    __builtin_amdgcn_global_load_lds((gas_u32p)g, (las_u32p)l, 16, 0, 0);
}

// ---------------- proto normalize (+ fused scratch zeroing) ----------------
__global__ __launch_bounds__(64) void proto_kernel(const float* __restrict__ pr,
                                                   const float* __restrict__ ps,
                                                   unsigned short* __restrict__ pn,
                                                   unsigned short* __restrict__ pnt,
                                                   float* __restrict__ zp) {
    int gid = blockIdx.x * 64 + threadIdx.x;           // 0..32767
    for (int i = gid; i < NZ_FLOATS; i += 32768) zp[i] = 0.f;

    int row = blockIdx.x & 255;
    int mod = blockIdx.x >> 8;
    const float* p = (mod ? ps : pr) + (size_t)row * 256;
    int lane = threadIdx.x;
    float4 v = ((const float4*)p)[lane];
    float ss = v.x * v.x + v.y * v.y + v.z * v.z + v.w * v.w;
    #pragma unroll
    for (int m = 1; m < 64; m <<= 1) ss += __shfl_xor(ss, m);
    float sc = 1.0f / (sqrtf(ss) + EPS);
    ushort4 u4;
    u4.x = f2bf(v.x * sc); u4.y = f2bf(v.y * sc);
    u4.z = f2bf(v.z * sc); u4.w = f2bf(v.w * sc);
    *(ushort4*)(pn + (size_t)mod * 65536 + (size_t)row * 256 + lane * 4) = u4;
    unsigned short* pt = pnt + (size_t)mod * 65536 + row;
    pt[(size_t)(lane * 4 + 0) * 256] = u4.x;
    pt[(size_t)(lane * 4 + 1) * 256] = u4.y;
    pt[(size_t)(lane * 4 + 2) * 256] = u4.z;
    pt[(size_t)(lane * 4 + 3) * 256] = u4.w;
}

// ---------------- GEMM0 fused with prep: normalize f rows -> A resident in LDS ----------------
// A full-K resident [128 rows][256 k] bf16, 8-short-chunk XOR swizzle keyed on (row&7).
// B (pn panel) staged per-kh [128 cols][64 k] via global_load_lds (verified pattern).
// LDS 64+16 = 80 KB -> 2 blocks/CU. Epilogue: sim f32, qb bf16, Tg atomics (round-3 verified).
__global__ __launch_bounds__(256) void gemm0_fused(const float* __restrict__ fr,
                                                   const float* __restrict__ fs,
                                                   const unsigned short* __restrict__ pn,
                                                   unsigned short* __restrict__ qb,
                                                   float* __restrict__ doutf,
                                                   float* __restrict__ Tg) {
    __shared__ __align__(16) char smem[81920];
    short* Afull = (short*)smem;             // 65536 B
    short* Bl    = (short*)(smem + 65536);   // 16384 B (per-kh)

    int bx = blockIdx.x, by = blockIdx.y, mod = blockIdx.z;
    int t = threadIdx.x, lane = t & 63, wv = t >> 6;
    int wrow = (wv >> 1) * 64, wcol = (wv & 1) * 64;
    int g = lane >> 4, ml = lane & 15;

    const float* F0 = (mod ? fs : fr) + (size_t)by * 128 * 256;
    const unsigned short* B0 = pn + (size_t)mod * 65536 + (size_t)bx * 128 * 256;

    // ---- build A: normalize rows (identical 64-lane butterfly as old prep) ----
    for (int bs = 0; bs < 4; bs++) {
        int rbase = wv * 32 + bs * 8;
        float4 vv[8];
        #pragma unroll
        for (int i = 0; i < 8; i++)
            vv[i] = ((const float4*)(F0 + (size_t)(rbase + i) * 256))[lane];
        #pragma unroll
        for (int i = 0; i < 8; i++) {
            float ss = vv[i].x * vv[i].x + vv[i].y * vv[i].y
                     + vv[i].z * vv[i].z + vv[i].w * vv[i].w;
            #pragma unroll
            for (int m = 1; m < 64; m <<= 1) ss += __shfl_xor(ss, m);
            float sc = 1.0f / (sqrtf(ss) + EPS);
            ushort4 u4;
            u4.x = f2bf(vv[i].x * sc); u4.y = f2bf(vv[i].y * sc);
            u4.z = f2bf(vv[i].z * sc); u4.w = f2bf(vv[i].w * sc);
            int row = rbase + i;
            int off = row * 256 + (((lane >> 1) ^ (row & 7)) << 3) + ((lane & 1) << 2);
            *(ushort4*)&Afull[off] = u4;
        }
    }

    floatx4 acc[4][4];
    #pragma unroll
    for (int i = 0; i < 4; i++)
        #pragma unroll
        for (int j = 0; j < 4; j++) acc[i][j] = (floatx4){0.f, 0.f, 0.f, 0.f};

    for (int kh = 0; kh < 4; kh++) {
        // stage B chunk [128 cols][64 k] (verified swizzle, keyed on col&7)
        #pragma unroll
        for (int i = 0; i < 4; i++) {
            int sI = i * 256 + t;
            int r = sI >> 3, cs = sI & 7;
            int cg = cs ^ (r & 7);
            size_t goff = (size_t)r * 256 + kh * 64 + cg * 8;
            lds_cp16(B0 + goff, &Bl[sI * 8]);
        }
        __syncthreads();                      // kh=0: also publishes A build
        #pragma unroll
        for (int ks = 0; ks < 2; ks++) {
            short8 af[4], bfr[4];
            int c = ks * 4 + g;
            int c8 = kh * 8 + c;
            #pragma unroll
            for (int mt = 0; mt < 4; mt++) {
                int row = wrow + mt * 16 + ml;
                af[mt] = *(const short8*)&Afull[row * 256 + ((c8 ^ (row & 7)) << 3)];
            }
            #pragma unroll
            for (int nt = 0; nt < 4; nt++) {
                int col = wcol + nt * 16 + ml;
                bfr[nt] = *(const short8*)&Bl[col * 64 + ((c ^ (col & 7)) << 3)];
            }
            #pragma unroll
            for (int mt = 0; mt < 4; mt++)
                #pragma unroll
                for (int nt = 0; nt < 4; nt++)
                    acc[mt][nt] = __builtin_amdgcn_mfma_f32_16x16x32_bf16(af[mt], bfr[nt], acc[mt][nt], 0, 0, 0);
        }
        __syncthreads();
    }

    // epilogue: sim f32 + q bf16 + Tg (C/D layout col=lane&15, row=(lane>>4)*4+reg)
    int g4 = g << 2;
    float tsum = 0.f;
    #pragma unroll
    for (int mt = 0; mt < 4; mt++)
        #pragma unroll
        for (int nt = 0; nt < 4; nt++)
            #pragma unroll
            for (int reg = 0; reg < 4; reg++) {
                float s = acc[mt][nt][reg];
                int row = by * 128 + wrow + mt * 16 + g4 + reg;
                int col = bx * 128 + wcol + nt * 16 + ml;
                size_t idx = (size_t)row * 256 + col;
                doutf[OUT_SIM + (size_t)mod * PM + idx] = s;
                unsigned short eb = f2bf(__expf(s * 20.0f));   // exp(sim/tau), tau=0.05
                qb[(size_t)mod * PM + idx] = eb;
                tsum += bf2f(eb);
            }
    #pragma unroll
    for (int mk = 1; mk < 64; mk <<= 1) tsum += __shfl_xor(tsum, mk);
    float* tred = (float*)(smem + 65536);     // Bl dead after last sync
    if (lane == 0) tred[wv] = tsum;
    __syncthreads();
    if (t == 0) atomicAdd(&Tg[mod * 16 + (by >> 3)], tred[0] + tred[1] + tred[2] + tred[3]);
}

// ---------------- Sinkhorn passes 1..5 (verified kernel, pass-6 path removed) ----------------
__global__ __launch_bounds__(256) void pass_kernel(const unsigned short* __restrict__ qbg,
                                                   float* __restrict__ u,
                                                   const float* __restrict__ Tg,
                                                   float* __restrict__ Sc,
                                                   int pass) {
    __shared__ float vcur[256];
    __shared__ float unl[32];
    __shared__ float wsum[4][256];
    int tile = blockIdx.x, b = blockIdx.y, mod = blockIdx.z;
    int t = threadIdx.x;
    {
        float v = 1.0f;
        for (int j = 1; j < pass; j++) {
            float sc = Sc[((size_t)(mod * 6 + j) * 16 + b) * 256 + t];
            v = v * (1.0f / 256.0f) / (v * sc + EPS);
        }
        vcur[t] = v;
    }
    __syncthreads();

    int r = t >> 3, q = t & 7;
    size_t row = (size_t)b * 1024 + tile * 32 + r;
    const unsigned short* qrow = qbg + ((size_t)mod * M + row) * 256;
    const short8* q8 = (const short8*)(qrow + q * 32);
    const float4* v4 = (const float4*)(vcur + q * 32);
    float sr = 0.f;
    #pragma unroll
    for (int i = 0; i < 4; i++) {
        short8 qv = q8[i];
        float4 va = v4[2 * i], vb = v4[2 * i + 1];
        sr += bf2f((unsigned short)qv[0]) * va.x + bf2f((unsigned short)qv[1]) * va.y
            + bf2f((unsigned short)qv[2]) * va.z + bf2f((unsigned short)qv[3]) * va.w
            + bf2f((unsigned short)qv[4]) * vb.x + bf2f((unsigned short)qv[5]) * vb.y
            + bf2f((unsigned short)qv[6]) * vb.z + bf2f((unsigned short)qv[7]) * vb.w;
    }
    sr += __shfl_xor(sr, 1);
    sr += __shfl_xor(sr, 2);
    sr += __shfl_xor(sr, 4);

    float up = (pass == 1) ? 1.0f / (Tg[mod * 16 + b] + EPS) : u[(size_t)mod * M + row];
    float un = up * (1.0f / 1024.0f) / (up * sr + EPS);
    if (q == 0) {
        u[(size_t)mod * M + row] = un;
        unl[r] = un;
    }
    __syncthreads();

    int wv = t >> 6, lane = t & 63;
    float c0 = 0.f, c1 = 0.f, c2 = 0.f, c3 = 0.f;
    size_t rowbase = (size_t)mod * M + (size_t)b * 1024 + tile * 32;
    #pragma unroll
    for (int rr8 = 0; rr8 < 8; rr8++) {
        int rr = wv * 8 + rr8;
        float unr = unl[rr];
        ushort4 qv = *(const ushort4*)(qbg + (rowbase + rr) * 256 + lane * 4);
        c0 += bf2f(qv.x) * unr;
        c1 += bf2f(qv.y) * unr;
        c2 += bf2f(qv.z) * unr;
        c3 += bf2f(qv.w) * unr;
    }
    *(float4*)&wsum[wv][lane * 4] = make_float4(c0, c1, c2, c3);
    __syncthreads();
    {
        float ssum = wsum[0][t] + wsum[1][t] + wsum[2][t] + wsum[3][t];
        atomicAdd(&Sc[((size_t)(mod * 6 + pass) * 16 + b) * 256 + t], ssum);
    }
}

// ---------------- GEMM1 fused with pass 6: build assign from q,u,v -> z ----------------
// Phase 0: v5 chain from Sc[1..5] (same arithmetic as pass_kernel prologue at pass=6).
// Phase 1: sr/un per row (same 8-lane pattern as pass_kernel phase A, pass-6 formula).
// Phase 2: a = q*u*v -> assign f32 global (bx==0), bf16 swizzled into A-full LDS, cs partials.
// Phase 3: MFMA vs pnt panel (per-kh staged), z epilogue. LDS 80 KB -> 2 blocks/CU.
__global__ __launch_bounds__(256) void gemm1_fused(const unsigned short* __restrict__ qbg,
                                                   const unsigned short* __restrict__ pnt,
                                                   const float* __restrict__ u,
                                                   const float* __restrict__ Sc,
                                                   float* __restrict__ cs,
                                                   float* __restrict__ doutf) {
    __shared__ __align__(16) char smem[81920];
    short* Afull = (short*)smem;                     // 65536 B
    short* Bl    = (short*)(smem + 65536);           // 16384 B (phase 3)
    float* vl    = (float*)(smem + 65536);           // overlay: 256 f32 (build)
    float* unl   = (float*)(smem + 65536 + 1024);    // overlay: 128 f32
    float* wsum  = (float*)(smem + 65536 + 2048);    // overlay: 4*256 f32

    int bx = blockIdx.x, by = blockIdx.y, mod = blockIdx.z;
    int b = by >> 3;
    int t = threadIdx.x, lane = t & 63, wv = t >> 6;
    int wrow = (wv >> 1) * 64, wcol = (wv & 1) * 64;
    int g = lane >> 4, ml = lane & 15;
    int r = t >> 3, q = t & 7;
    size_t rowg0 = (size_t)by * 128;

    // ---- phase 0: v5 chain ----
    if (t < 256) {
        float v = 1.0f;
        #pragma unroll
        for (int j = 1; j <= 5; j++) {
            float scv = Sc[((size_t)(mod * 6 + j) * 16 + b) * 256 + t];
            v = v * (1.0f / 256.0f) / (v * scv + EPS);
        }
        vl[t] = v;
    }
    __syncthreads();

    // ---- phase 1: sr -> un per row (4 sweeps x 32 rows) ----
    const float* vb0 = vl + q * 32;
    for (int s = 0; s < 4; s++) {
        int rl = s * 32 + r;
        size_t rowg = rowg0 + rl;
        const short8* q8 = (const short8*)(qbg + ((size_t)mod * PM + rowg * 256) + q * 32);
        float sr = 0.f;
        #pragma unroll
        for (int i = 0; i < 4; i++) {
            short8 qv = q8[i];
            float4 va = *(const float4*)(vb0 + i * 8);
            float4 vb = *(const float4*)(vb0 + i * 8 + 4);
            sr += bf2f((unsigned short)qv[0]) * va.x + bf2f((unsigned short)qv[1]) * va.y
                + bf2f((unsigned short)qv[2]) * va.z + bf2f((unsigned short)qv[3]) * va.w
                + bf2f((unsigned short)qv[4]) * vb.x + bf2f((unsigned short)qv[5]) * vb.y
                + bf2f((unsigned short)qv[6]) * vb.z + bf2f((unsigned short)qv[7]) * vb.w;
        }
        sr += __shfl_xor(sr, 1);
        sr += __shfl_xor(sr, 2);
        sr += __shfl_xor(sr, 4);
        float up = u[(size_t)mod * M + rowg];
        float un = up / (up * sr + EPS);               // pass-6 formula
        if (q == 0) unl[rl] = un;
    }
    __syncthreads();

    // ---- phase 2: a = q*un*v -> assign (bx==0), swizzled bf16 A, cs partials ----
    {
        float c0 = 0.f, c1 = 0.f, c2 = 0.f, c3 = 0.f;
        float4 vv = *(const float4*)(vl + lane * 4);
        float* aout = doutf + OUT_ASSIGN + (size_t)mod * PM;
        for (int s = 0; s < 4; s++) {
            #pragma unroll
            for (int k = 0; k < 8; k++) {
                int rl = s * 32 + wv * 8 + k;
                size_t rowg = rowg0 + rl;
                float unr = unl[rl];
                ushort4 qv = *(const ushort4*)(qbg + ((size_t)mod * PM + rowg * 256) + lane * 4);
                float4 a = make_float4(bf2f(qv.x) * unr * vv.x, bf2f(qv.y) * unr * vv.y,
                                       bf2f(qv.z) * unr * vv.z, bf2f(qv.w) * unr * vv.w);
                if (bx == 0) *(float4*)(aout + rowg * 256 + lane * 4) = a;
                ushort4 o;
                o.x = f2bf(a.x); o.y = f2bf(a.y); o.z = f2bf(a.z); o.w = f2bf(a.w);
                int off = rl * 256 + (((lane >> 1) ^ (rl & 7)) << 3) + ((lane & 1) << 2);
                *(ushort4*)&Afull[off] = o;
                c0 += a.x; c1 += a.y; c2 += a.z; c3 += a.w;
            }
        }
        *(float4*)&wsum[wv * 256 + lane * 4] = make_float4(c0, c1, c2, c3);
    }
    __syncthreads();
    if (bx == 0 && t < 256) {
        float ssum = wsum[0 * 256 + t] + wsum[1 * 256 + t] + wsum[2 * 256 + t] + wsum[3 * 256 + t];
        atomicAdd(&cs[((size_t)mod * 16 + b) * 256 + t], ssum);
    }
    __syncthreads();                                   // wsum reads done before Bl staging

    // ---- phase 3: MFMA vs pnt ----
    const unsigned short* B0 = pnt + (size_t)mod * 65536 + (size_t)bx * 128 * 256;
    floatx4 acc[4][4];
    #pragma unroll
    for (int i = 0; i < 4; i++)
        #pragma unroll
        for (int j = 0; j < 4; j++) acc[i][j] = (floatx4){0.f, 0.f, 0.f, 0.f};

    for (int kh = 0; kh < 4; kh++) {
        #pragma unroll
        for (int i = 0; i < 4; i++) {
            int sI = i * 256 + t;
            int rr = sI >> 3, cc = sI & 7;
            int cg = cc ^ (rr & 7);
            size_t goff = (size_t)rr * 256 + kh * 64 + cg * 8;
            lds_cp16(B0 + goff, &Bl[sI * 8]);
        }
        __syncthreads();
        #pragma unroll
        for (int ks = 0; ks < 2; ks++) {
            short8 af[4], bfr[4];
            int c = ks * 4 + g;
            int c8 = kh * 8 + c;
            #pragma unroll
            for (int mt = 0; mt < 4; mt++) {
                int row = wrow + mt * 16 + ml;
                af[mt] = *(const short8*)&Afull[row * 256 + ((c8 ^ (row & 7)) << 3)];
            }
            #pragma unroll
            for (int nt = 0; nt < 4; nt++) {
                int col = wcol + nt * 16 + ml;
                bfr[nt] = *(const short8*)&Bl[col * 64 + ((c ^ (col & 7)) << 3)];
            }
            #pragma unroll
            for (int mt = 0; mt < 4; mt++)
                #pragma unroll
                for (int nt = 0; nt < 4; nt++)
                    acc[mt][nt] = __builtin_amdgcn_mfma_f32_16x16x32_bf16(af[mt], bfr[nt], acc[mt][nt], 0, 0, 0);
        }
        __syncthreads();
    }

    int g4 = g << 2;
    float* dst = doutf + OUT_Z + (size_t)mod * PM;
    #pragma unroll
    for (int mt = 0; mt < 4; mt++)
        #pragma unroll
        for (int nt = 0; nt < 4; nt++)
            #pragma unroll
            for (int reg = 0; reg < 4; reg++) {
                int row = by * 128 + wrow + mt * 16 + g4 + reg;
                int col = bx * 128 + wcol + nt * 16 + ml;
                dst[(size_t)row * 256 + col] = acc[mt][nt][reg];
            }
}

// ---------------- sem consistency scalar ----------------
__global__ __launch_bounds__(256) void sem_kernel(const float* __restrict__ cs,
                                                  float* __restrict__ doutf) {
    int t = threadIdx.x;
    float s = 0.f;
    #pragma unroll
    for (int b = 0; b < 16; b++)
        s += cs[b * 256 + t] * cs[4096 + b * 256 + t];
    #pragma unroll
    for (int mk = 1; mk < 64; mk <<= 1) s += __shfl_xor(s, mk);
    __shared__ float red[4];
    if ((t & 63) == 0) red[t >> 6] = s;
    __syncthreads();
    if (t == 0) {
        float tot = red[0] + red[1] + red[2] + red[3];
        float mv = tot / 16777216.0f;           // B*N*N
        mv = fminf(fmaxf(mv, 0.f), 1.f);
        doutf[OUT_SEM] = 1.0f - mv;
    }
}

extern "C" void kernel_launch(void* const* d_in, const int* in_sizes, int n_in,
                              void* d_out, int out_size, void* d_ws, size_t ws_size,
                              hipStream_t stream) {
    const float* f_rgb = (const float*)d_in[0];
    const float* f_sn  = (const float*)d_in[1];
    const float* p_rgb = (const float*)d_in[2];
    const float* p_sn  = (const float*)d_in[3];
    char* ws = (char*)d_ws;
    unsigned short* qb   = (unsigned short*)(ws + OFF_QB);
    unsigned short* pn   = (unsigned short*)(ws + OFF_PN);
    unsigned short* pnt  = (unsigned short*)(ws + OFF_PNT);
    float* u             = (float*)(ws + OFF_U);
    float* Tg            = (float*)(ws + OFF_T);
    float* Sc            = (float*)(ws + OFF_SC);
    float* cs            = (float*)(ws + OFF_CS);
    float* doutf         = (float*)d_out;

    proto_kernel<<<dim3(512), 64, 0, stream>>>(p_rgb, p_sn, pn, pnt, (float*)(ws + ZERO_OFF));
    gemm0_fused<<<dim3(2, 128, 2), 256, 0, stream>>>(f_rgb, f_sn, pn, qb, doutf, Tg);
    for (int p = 1; p <= 5; p++)
        pass_kernel<<<dim3(32, 16, 2), 256, 0, stream>>>(qb, u, Tg, Sc, p);
    gemm1_fused<<<dim3(2, 128, 2), 256, 0, stream>>>(qb, pnt, u, Sc, cs, doutf);
    sem_kernel<<<1, 256, 0, stream>>>(cs, doutf);
}